// Round 10
// baseline (84.869 us; speedup 1.0000x reference)
//
#include <hip/hip_runtime.h>
#include <math.h>

#define BATCH 65536
#define XPER  576               // 24*24 floats per image
#define NBLK  1024
#define WPB   4                 // waves per block
#define RPW   2                 // rounds per wave
#define IPR   8                 // images per wave-round
// block covers WPB*RPW*IPR = 64 images; wave-round chunk = 8 images = 4608 floats

// ws layout: slots[NBLK][8] partial sums (fully overwritten; no memset needed)

// ---------------------------------------------------------------- K1
// Fully-coalesced streaming + LDS scatter-add pooling.
// Instruction j, lane l reads chunk float4 #(j*64+l): 1 KB contiguous per
// wave instruction. Each float4 feeds 1-2 ds_add_f32 into a wave-private
// [8 img][16 cell] accumulator; DS in-order per wave => no barriers.
// Pool scale 1/36 cancels in prob = |U s|^2 / |s|^2 and is dropped.
__global__ __launch_bounds__(256) void circuit_kernel(
        const float* __restrict__ x, const float* __restrict__ params,
        float* __restrict__ out, float* __restrict__ slots) {
    __shared__ float sUr[16 * 20];     // U real, row r at r*20 (padded)
    __shared__ float sUi[16 * 20];     // U imag
    __shared__ float sg[48];           // 8 gates x {c,s,epr,epi,emr,emi}
    __shared__ float sacc[WPB][160];   // per-wave [8][16] accumulators (+pad)
    __shared__ float spart[8];

    const int t    = threadIdx.x;
    const int wid  = t >> 6;           // wave id (0..3)
    const int lane = t & 63;
    const int e    = lane >> 3;        // image within round (0..7)
    const int q    = lane & 7;         // owns state rows 2q, 2q+1

    if (t < 8) {
        spart[t] = 0.0f;
        float phi   = params[t * 3 + 0];
        float theta = params[t * 3 + 1];
        float omega = params[t * 3 + 2];
        float apo = 0.5f * (phi + omega), amo = 0.5f * (phi - omega);
        sg[t * 6 + 0] = cosf(0.5f * theta);
        sg[t * 6 + 1] = sinf(0.5f * theta);
        sg[t * 6 + 2] = cosf(apo);           // epr (ep = e^{-i(phi+omega)/2})
        sg[t * 6 + 3] = -sinf(apo);          // epi
        sg[t * 6 + 4] = cosf(amo);           // emr (em = e^{+i(phi-omega)/2})
        sg[t * 6 + 5] = sinf(amo);           // emi
    }
    __syncthreads();

    // ---- fold circuit into U (lane j owns column j of M; state' = M state)
    if (t < 16) {
        const int j = t;
        float Mr[16], Mi[16];
#pragma unroll
        for (int i = 0; i < 16; ++i) { Mr[i] = (i == j) ? 1.0f : 0.0f; Mi[i] = 0.0f; }
#pragma unroll
        for (int l = 0; l < 2; ++l) {
#pragma unroll
            for (int w = 0; w < 4; ++w) {
                const int g = l * 4 + w;
                float c   = sg[g * 6 + 0], s   = sg[g * 6 + 1];
                float epr = sg[g * 6 + 2], epi = sg[g * 6 + 3];
                float emr = sg[g * 6 + 4], emi = sg[g * 6 + 5];
                float m00r =  epr * c, m00i =  epi * c;
                float m01r = -emr * s, m01i = -emi * s;
                float m10r =  emr * s, m10i = -emi * s;
                float m11r =  epr * c, m11i = -epi * c;
                const int mask = 1 << (3 - w);
#pragma unroll
                for (int i = 0; i < 16; ++i) {
                    if (i & mask) continue;
                    int i1 = i | mask;
                    float r0 = Mr[i],  q0 = Mi[i];
                    float r1 = Mr[i1], q1 = Mi[i1];
                    Mr[i]  = m00r * r0 - m00i * q0 + m01r * r1 - m01i * q1;
                    Mi[i]  = m00r * q0 + m00i * r0 + m01r * q1 + m01i * r1;
                    Mr[i1] = m10r * r0 - m10i * q0 + m11r * r1 - m11i * q1;
                    Mi[i1] = m10r * q0 + m10i * r0 + m11r * q1 + m11i * r1;
                }
            }
            const int rr = (l % 3) + 1;
#pragma unroll
            for (int w = 0; w < 4; ++w) {
                int tq = (w + rr) & 3;
                int cb = 3 - w, tb = 3 - tq;
#pragma unroll
                for (int i = 0; i < 16; ++i) {
                    int pi = i ^ (((i >> cb) & 1) << tb);
                    if (pi > i) {
                        float tr = Mr[i]; Mr[i] = Mr[pi]; Mr[pi] = tr;
                        float ti = Mi[i]; Mi[i] = Mi[pi]; Mi[pi] = ti;
                    }
                }
            }
        }
#pragma unroll
        for (int i = 0; i < 16; ++i) {
            sUr[i * 20 + j] = Mr[i];
            sUi[i * 20 + j] = Mi[i];
        }
    }
    __syncthreads();

    // ---- precompute scatter targets (round-invariant: depend on j, lane)
    int accIdx[18];
    unsigned spMask = 0;
#pragma unroll
    for (int j = 0; j < 18; ++j) {
        int fidx = j * 256 + lane * 4;       // float index within 4608 chunk
        int img  = fidx / 576;
        int rem  = fidx - img * 576;
        int row  = rem / 24;
        int col  = rem - row * 24;
        int cc   = col / 6;
        accIdx[j] = img * 16 + (row / 6) * 4 + cc;
        if (col - cc * 6 == 4) spMask |= (1u << j);   // f4 straddles 2 cells
    }
    float* const accBase = &sacc[wid][0];

    // writer lane -> channel: z0@q=4, z1@q=2, z2@q=1, z3@q=0
    int c = -1;
    if      (q == 4) c = 0;
    else if (q == 2) c = 1;
    else if (q == 1) c = 2;
    else if (q == 0) c = 3;

    float accz = 0.0f, accz2 = 0.0f;
    const size_t blockImg = (size_t)blockIdx.x * (WPB * RPW * IPR);

#pragma unroll
    for (int rd = 0; rd < RPW; ++rd) {
        const size_t img0 = blockImg + (size_t)wid * (RPW * IPR) + (size_t)rd * IPR;
        const float* cb = x + img0 * XPER;

        // zero this wave's accumulators (in-order vs prior round's reads)
        accBase[lane]      = 0.0f;
        accBase[lane + 64] = 0.0f;

        // ---- two batches of 9 fully-coalesced loads + scatter-adds
#pragma unroll
        for (int b = 0; b < 2; ++b) {
            float4 r[9];
#pragma unroll
            for (int j2 = 0; j2 < 9; ++j2)
                r[j2] = *(const float4*)(cb + (b * 9 + j2) * 256 + lane * 4);
#pragma unroll
            for (int j2 = 0; j2 < 9; ++j2) {
                const int j = b * 9 + j2;
                float s01 = r[j2].x + r[j2].y;
                float s23 = r[j2].z + r[j2].w;
                bool  sp  = (spMask >> j) & 1;
                float sA  = sp ? s01 : (s01 + s23);
                atomicAdd(accBase + accIdx[j], sA);
                if (sp) atomicAdd(accBase + accIdx[j] + 1, s23);
            }
        }
        __builtin_amdgcn_sched_barrier(0);

        // ---- matvec for rows 2q,2q+1; vv and U via broadcast b128 reads
        float n2 = 0.0f, sr0 = 0.0f, si0 = 0.0f, sr1 = 0.0f, si1 = 0.0f;
#pragma unroll
        for (int m = 0; m < 4; ++m) {
            float4 v4 = *(const float4*)(accBase + e * 16 + 4 * m);
            float4 a0 = *(const float4*)(sUr + (2 * q) * 20 + 4 * m);
            float4 b0 = *(const float4*)(sUi + (2 * q) * 20 + 4 * m);
            float4 a1 = *(const float4*)(sUr + (2 * q + 1) * 20 + 4 * m);
            float4 b1 = *(const float4*)(sUi + (2 * q + 1) * 20 + 4 * m);
            n2  = fmaf(v4.x, v4.x, fmaf(v4.y, v4.y, fmaf(v4.z, v4.z, fmaf(v4.w, v4.w, n2))));
            sr0 = fmaf(a0.x, v4.x, fmaf(a0.y, v4.y, fmaf(a0.z, v4.z, fmaf(a0.w, v4.w, sr0))));
            si0 = fmaf(b0.x, v4.x, fmaf(b0.y, v4.y, fmaf(b0.z, v4.z, fmaf(b0.w, v4.w, si0))));
            sr1 = fmaf(a1.x, v4.x, fmaf(a1.y, v4.y, fmaf(a1.z, v4.z, fmaf(a1.w, v4.w, sr1))));
            si1 = fmaf(b1.x, v4.x, fmaf(b1.y, v4.y, fmaf(b1.z, v4.z, fmaf(b1.w, v4.w, si1))));
        }
        float inv = 1.0f / n2;                 // 1/36 pool scale cancels here
        float p0 = (sr0 * sr0 + si0 * si0) * inv;
        float p1 = (sr1 * sr1 + si1 * si1) * inv;

        // ---- WHT: bit0 in-register, bits 1..3 via 8-lane butterflies
        float u = p0 + p1, d = p0 - p1, o;
        o = __shfl_xor(u, 1); u = (q & 1) ? (o - u) : (u + o);
        o = __shfl_xor(u, 2); u = (q & 2) ? (o - u) : (u + o);
        o = __shfl_xor(u, 4); u = (q & 4) ? (o - u) : (u + o);
        d += __shfl_xor(d, 1);
        d += __shfl_xor(d, 2);
        d += __shfl_xor(d, 4);

        float z = (q == 0) ? d : u;
        if (c >= 0) { accz += z; accz2 += z * z; }

        // ---- pack the 4 channels to lane q==0, one float4 store per image
        int gb = lane & ~7;
        float z0 = __shfl(z, gb | 4);
        float z1 = __shfl(z, gb | 2);
        float z2 = __shfl(z, gb | 1);
        if (q == 0)
            ((float4*)out)[img0 + e] = make_float4(z0, z1, z2, z);
    }

    // ---- per-block partials -> private slot (no global atomics, no memset)
    if (c >= 0) {
        atomicAdd(&spart[c], accz);
        atomicAdd(&spart[4 + c], accz2);
    }
    __syncthreads();
    if (t < 8) slots[blockIdx.x * 8 + t] = spart[t];
}

// ---------------------------------------------------------------- K2
// Reduce per-block slots + finalize BN stats + apply affine in place.
__global__ __launch_bounds__(256) void bn_apply(float* __restrict__ out,
                                                const float* __restrict__ slots,
                                                const float* __restrict__ gamma,
                                                const float* __restrict__ beta) {
    __shared__ float red[256];
    __shared__ float sc[8];
    const int t = threadIdx.x;
    const int ch = t & 7, g = t >> 3;      // g in 0..31
    float s = 0.0f;
#pragma unroll
    for (int k = 0; k < NBLK / 32; ++k)
        s += slots[(size_t)(g + 32 * k) * 8 + ch];
    red[t] = s;
    __syncthreads();
#pragma unroll
    for (int stp = 128; stp >= 8; stp >>= 1) {
        if (t < stp) red[t] += red[t + stp];
        __syncthreads();
    }
    if (t < 4) {
        float mu  = red[t] * (1.0f / BATCH);
        float var = red[4 + t] * (1.0f / BATCH) - mu * mu;
        float a = gamma[t] * rsqrtf(var + 1e-5f);
        sc[t]     = a;
        sc[4 + t] = beta[t] - mu * a;
    }
    __syncthreads();
    int i = blockIdx.x * 256 + t;   // one float4 (one image) each
    float4 z = ((float4*)out)[i];
    z.x = fmaf(z.x, sc[0], sc[4]);
    z.y = fmaf(z.y, sc[1], sc[5]);
    z.z = fmaf(z.z, sc[2], sc[6]);
    z.w = fmaf(z.w, sc[3], sc[7]);
    ((float4*)out)[i] = z;
}

extern "C" void kernel_launch(void* const* d_in, const int* in_sizes, int n_in,
                              void* d_out, int out_size, void* d_ws, size_t ws_size,
                              hipStream_t stream) {
    const float* x      = (const float*)d_in[0];
    const float* params = (const float*)d_in[1];
    const float* gamma  = (const float*)d_in[2];
    const float* beta   = (const float*)d_in[3];
    float* out = (float*)d_out;
    float* ws  = (float*)d_ws;

    hipLaunchKernelGGL(circuit_kernel, dim3(NBLK), dim3(256), 0, stream,
                       x, params, out, ws);
    hipLaunchKernelGGL(bn_apply, dim3(BATCH / 256), dim3(256), 0, stream,
                       out, ws, gamma, beta);
}

// Round 11
// 36.228 us; speedup vs baseline: 2.3427x; 2.3427x over previous
//
#include <hip/hip_runtime.h>
#include <math.h>

#define BATCH 65536
#define XPER  576               // 24*24 floats per image
#define NBLK  2048
#define WPB   4                 // waves per block
#define IPR   8                 // images per wave
// block covers WPB*IPR = 32 images

// ws layout: slots[NBLK][8] partial sums (fully overwritten; no memset needed)

// ---------------------------------------------------------------- K1
// Direct-from-global pooling (R9 structure), U in padded LDS (low VGPR ->
// high occupancy). Lane = (image e, cell-pair q); 18 aligned float4 loads
// cover the 12x6 strip; lane's pooled cells (2q,2q+1) are its matvec rows.
__global__ __launch_bounds__(256) void circuit_kernel(
        const float* __restrict__ x, const float* __restrict__ params,
        float* __restrict__ out, float* __restrict__ slots) {
    __shared__ float sUr[16 * 20];     // U real, row r at r*20 (padded)
    __shared__ float sUi[16 * 20];     // U imag
    __shared__ float sg[48];           // 8 gates x {c,s,epr,epi,emr,emi}
    __shared__ float sv[WPB][IPR * 20];// per-wave pooled-v strips (padded)
    __shared__ float spart[8];

    const int t    = threadIdx.x;
    const int wid  = t >> 6;           // wave id (0..3)
    const int lane = t & 63;
    const int e    = lane >> 3;        // image within wave (0..7)
    const int q    = lane & 7;         // cell pair (covers cells 2q, 2q+1)
    const int pr   = q >> 1;           // cell row (0..3)
    const int P    = q & 1;            // pair column (0..1)

    if (t < 8) {
        spart[t] = 0.0f;
        float phi   = params[t * 3 + 0];
        float theta = params[t * 3 + 1];
        float omega = params[t * 3 + 2];
        float apo = 0.5f * (phi + omega), amo = 0.5f * (phi - omega);
        sg[t * 6 + 0] = cosf(0.5f * theta);
        sg[t * 6 + 1] = sinf(0.5f * theta);
        sg[t * 6 + 2] = cosf(apo);           // epr (ep = e^{-i(phi+omega)/2})
        sg[t * 6 + 3] = -sinf(apo);          // epi
        sg[t * 6 + 4] = cosf(amo);           // emr (em = e^{+i(phi-omega)/2})
        sg[t * 6 + 5] = sinf(amo);           // emi
    }
    __syncthreads();

    // ---- fold circuit into U (lane j owns column j of M; state' = M state)
    if (t < 16) {
        const int j = t;
        float Mr[16], Mi[16];
#pragma unroll
        for (int i = 0; i < 16; ++i) { Mr[i] = (i == j) ? 1.0f : 0.0f; Mi[i] = 0.0f; }
#pragma unroll
        for (int l = 0; l < 2; ++l) {
#pragma unroll
            for (int w = 0; w < 4; ++w) {
                const int g = l * 4 + w;
                float c   = sg[g * 6 + 0], s   = sg[g * 6 + 1];
                float epr = sg[g * 6 + 2], epi = sg[g * 6 + 3];
                float emr = sg[g * 6 + 4], emi = sg[g * 6 + 5];
                float m00r =  epr * c, m00i =  epi * c;
                float m01r = -emr * s, m01i = -emi * s;
                float m10r =  emr * s, m10i = -emi * s;
                float m11r =  epr * c, m11i = -epi * c;
                const int mask = 1 << (3 - w);
#pragma unroll
                for (int i = 0; i < 16; ++i) {
                    if (i & mask) continue;
                    int i1 = i | mask;
                    float r0 = Mr[i],  q0 = Mi[i];
                    float r1 = Mr[i1], q1 = Mi[i1];
                    Mr[i]  = m00r * r0 - m00i * q0 + m01r * r1 - m01i * q1;
                    Mi[i]  = m00r * q0 + m00i * r0 + m01r * q1 + m01i * r1;
                    Mr[i1] = m10r * r0 - m10i * q0 + m11r * r1 - m11i * q1;
                    Mi[i1] = m10r * q0 + m10i * r0 + m11r * q1 + m11i * r1;
                }
            }
            const int rr = (l % 3) + 1;
#pragma unroll
            for (int w = 0; w < 4; ++w) {
                int tq = (w + rr) & 3;
                int cb = 3 - w, tb = 3 - tq;
#pragma unroll
                for (int i = 0; i < 16; ++i) {
                    int pi = i ^ (((i >> cb) & 1) << tb);
                    if (pi > i) {
                        float tr = Mr[i]; Mr[i] = Mr[pi]; Mr[pi] = tr;
                        float ti = Mi[i]; Mi[i] = Mi[pi]; Mi[pi] = ti;
                    }
                }
            }
        }
#pragma unroll
        for (int i = 0; i < 16; ++i) {
            sUr[i * 20 + j] = Mr[i];
            sUi[i * 20 + j] = Mi[i];
        }
    }
    __syncthreads();

    // writer lane -> channel: z0@q=4, z1@q=2, z2@q=1, z3@q=0
    int c = -1;
    if      (q == 4) c = 0;
    else if (q == 2) c = 1;
    else if (q == 1) c = 2;
    else if (q == 0) c = 3;

    const int cbase = pr * 144 + P * 12;   // strip base within image (floats)
    const size_t img0 = (size_t)blockIdx.x * 32 + (size_t)wid * IPR;
    const size_t img  = img0 + e;
    const float* ip = x + img * XPER + cbase;

    // ---- pool the 12x6 strip: 18 aligned float4 loads, two cell sums
    float L = 0.0f, R = 0.0f;
#pragma unroll
    for (int r = 0; r < 6; ++r) {
        float4 a = *(const float4*)(ip + r * 24);
        float4 b = *(const float4*)(ip + r * 24 + 4);
        float4 d = *(const float4*)(ip + r * 24 + 8);
        L += a.x + a.y + a.z + a.w + b.x + b.y;
        R += b.z + b.w + d.x + d.y + d.z + d.w;
    }
    float vL = L * (1.0f / 36.0f), vR = R * (1.0f / 36.0f);

    // ---- redistribute via per-wave padded strip (write b64, 4x b128
    // broadcast reads; wave-private + DS in-order => no barrier)
    *(float2*)(&sv[wid][e * 20 + 2 * q]) = make_float2(vL, vR);

    // ---- matvec for state rows 2q, 2q+1; vv and U via b128 LDS reads
    float n2 = 0.0f, sr0 = 0.0f, si0 = 0.0f, sr1 = 0.0f, si1 = 0.0f;
#pragma unroll
    for (int m = 0; m < 4; ++m) {
        float4 v4 = *(const float4*)(&sv[wid][e * 20 + 4 * m]);
        float4 a0 = *(const float4*)(sUr + (2 * q) * 20 + 4 * m);
        float4 b0 = *(const float4*)(sUi + (2 * q) * 20 + 4 * m);
        float4 a1 = *(const float4*)(sUr + (2 * q + 1) * 20 + 4 * m);
        float4 b1 = *(const float4*)(sUi + (2 * q + 1) * 20 + 4 * m);
        n2  = fmaf(v4.x, v4.x, fmaf(v4.y, v4.y, fmaf(v4.z, v4.z, fmaf(v4.w, v4.w, n2))));
        sr0 = fmaf(a0.x, v4.x, fmaf(a0.y, v4.y, fmaf(a0.z, v4.z, fmaf(a0.w, v4.w, sr0))));
        si0 = fmaf(b0.x, v4.x, fmaf(b0.y, v4.y, fmaf(b0.z, v4.z, fmaf(b0.w, v4.w, si0))));
        sr1 = fmaf(a1.x, v4.x, fmaf(a1.y, v4.y, fmaf(a1.z, v4.z, fmaf(a1.w, v4.w, sr1))));
        si1 = fmaf(b1.x, v4.x, fmaf(b1.y, v4.y, fmaf(b1.z, v4.z, fmaf(b1.w, v4.w, si1))));
    }
    float inv = 1.0f / n2;
    float p0 = (sr0 * sr0 + si0 * si0) * inv;
    float p1 = (sr1 * sr1 + si1 * si1) * inv;

    // ---- WHT: bit0 in-register, bits 1..3 via 8-lane butterflies
    float u = p0 + p1, d = p0 - p1, o;
    o = __shfl_xor(u, 1); u = (q & 1) ? (o - u) : (u + o);
    o = __shfl_xor(u, 2); u = (q & 2) ? (o - u) : (u + o);
    o = __shfl_xor(u, 4); u = (q & 4) ? (o - u) : (u + o);
    d += __shfl_xor(d, 1);
    d += __shfl_xor(d, 2);
    d += __shfl_xor(d, 4);

    float z = (q == 0) ? d : u;

    // ---- pack the 4 channels to lane q==0, one float4 store per image
    int gb = lane & ~7;
    float z0 = __shfl(z, gb | 4);
    float z1 = __shfl(z, gb | 2);
    float z2 = __shfl(z, gb | 1);
    if (q == 0)
        ((float4*)out)[img] = make_float4(z0, z1, z2, z);

    // ---- per-block partials -> private slot (no global atomics, no memset)
    if (c >= 0) {
        atomicAdd(&spart[c], z);
        atomicAdd(&spart[4 + c], z * z);
    }
    __syncthreads();
    if (t < 8) slots[blockIdx.x * 8 + t] = spart[t];
}

// ---------------------------------------------------------------- K2
// Reduce per-block slots + finalize BN stats + apply affine in place.
__global__ __launch_bounds__(256) void bn_apply(float* __restrict__ out,
                                                const float* __restrict__ slots,
                                                const float* __restrict__ gamma,
                                                const float* __restrict__ beta) {
    __shared__ float red[256];
    __shared__ float sc[8];
    const int t = threadIdx.x;
    const int ch = t & 7, g = t >> 3;      // g in 0..31
    float s = 0.0f;
#pragma unroll
    for (int k = 0; k < NBLK / 32; ++k)
        s += slots[(size_t)(g + 32 * k) * 8 + ch];
    red[t] = s;
    __syncthreads();
#pragma unroll
    for (int stp = 128; stp >= 8; stp >>= 1) {
        if (t < stp) red[t] += red[t + stp];
        __syncthreads();
    }
    if (t < 4) {
        float mu  = red[t] * (1.0f / BATCH);
        float var = red[4 + t] * (1.0f / BATCH) - mu * mu;
        float a = gamma[t] * rsqrtf(var + 1e-5f);
        sc[t]     = a;
        sc[4 + t] = beta[t] - mu * a;
    }
    __syncthreads();
    int i = blockIdx.x * 256 + t;   // one float4 (one image) each
    float4 z = ((float4*)out)[i];
    z.x = fmaf(z.x, sc[0], sc[4]);
    z.y = fmaf(z.y, sc[1], sc[5]);
    z.z = fmaf(z.z, sc[2], sc[6]);
    z.w = fmaf(z.w, sc[3], sc[7]);
    ((float4*)out)[i] = z;
}

extern "C" void kernel_launch(void* const* d_in, const int* in_sizes, int n_in,
                              void* d_out, int out_size, void* d_ws, size_t ws_size,
                              hipStream_t stream) {
    const float* x      = (const float*)d_in[0];
    const float* params = (const float*)d_in[1];
    const float* gamma  = (const float*)d_in[2];
    const float* beta   = (const float*)d_in[3];
    float* out = (float*)d_out;
    float* ws  = (float*)d_ws;

    hipLaunchKernelGGL(circuit_kernel, dim3(NBLK), dim3(256), 0, stream,
                       x, params, out, ws);
    hipLaunchKernelGGL(bn_apply, dim3(BATCH / 256), dim3(256), 0, stream,
                       out, ws, gamma, beta);
}